// Round 1
// baseline (2188.426 us; speedup 1.0000x reference)
//
#include <hip/hip_runtime.h>

#define T_LEN 512
#define B_SZ  64
#define I_SZ  512
#define H_SZ  512

using half8   = __attribute__((ext_vector_type(8))) _Float16;
using float4v = __attribute__((ext_vector_type(4))) float;

__device__ __forceinline__ float fast_tanh(float x) {
    // 1 - 2/(e^{2x}+1): monotone, saturates to +/-1, no NaN (inf -> 1, 0 -> -1)
    float e = __expf(2.0f * x);
    return 1.0f - 2.0f * __builtin_amdgcn_rcpf(e + 1.0f);
}

// ---------------------------------------------------------------------------
// Kernel 1: input projection GEMM (f16 MFMA, fp32 accumulate) — unchanged.
// ---------------------------------------------------------------------------
__global__ __launch_bounds__(256) void xproj_kernel(
    const float* __restrict__ x,
    const float* __restrict__ Wf, const float* __restrict__ bf,
    const float* __restrict__ Wb, const float* __restrict__ bb,
    _Float16* __restrict__ xp)
{
    __shared__ _Float16 Ash[64][72];
    __shared__ _Float16 Bsh[64][72];

    const int bid = blockIdx.x;
    const int dir = bid & 1;
    const int nt  = (bid >> 1) & 7;
    const int t   = bid >> 4;
    const float* __restrict__ W    = dir ? Wb : Wf;
    const float* __restrict__ bias = dir ? bb : bf;
    const int n0 = nt * 64;

    const int tid  = threadIdx.x;
    const int row  = tid >> 2;
    const int part = tid & 3;
    const int wv   = tid >> 6;
    const int lane = tid & 63;
    const int lm   = lane & 15;
    const int lq   = lane >> 4;

    float4v acc[4] = {{0,0,0,0},{0,0,0,0},{0,0,0,0},{0,0,0,0}};

    const float* ap = x + ((size_t)row * T_LEN + t) * I_SZ + part * 16;
    const float* bp = W + ((size_t)(n0 + row)) * I_SZ + part * 16;

    for (int k0 = 0; k0 < I_SZ; k0 += 64) {
        float areg[16], breg[16];
        #pragma unroll
        for (int i = 0; i < 16; i++) { areg[i] = ap[k0 + i]; breg[i] = bp[k0 + i]; }
        __syncthreads();
        #pragma unroll
        for (int i = 0; i < 16; i++) {
            Ash[row][part*16 + i] = (_Float16)areg[i];
            Bsh[row][part*16 + i] = (_Float16)breg[i];
        }
        __syncthreads();
        #pragma unroll
        for (int ks = 0; ks < 2; ks++) {
            half8 afr = *(const half8*)&Ash[16*wv + lm][ks*32 + lq*8];
            #pragma unroll
            for (int ns = 0; ns < 4; ns++) {
                half8 bfr = *(const half8*)&Bsh[ns*16 + lm][ks*32 + lq*8];
                acc[ns] = __builtin_amdgcn_mfma_f32_16x16x32_f16(afr, bfr, acc[ns], 0, 0, 0);
            }
        }
    }

    #pragma unroll
    for (int ns = 0; ns < 4; ns++) {
        const int n = n0 + ns*16 + lm;
        const float bv = bias[n];
        #pragma unroll
        for (int j = 0; j < 4; j++) {
            const int b = 16*wv + lq*4 + j;
            xp[(((size_t)dir*T_LEN + t)*B_SZ + b)*H_SZ + n] = (_Float16)(acc[ns][j] + bv);
        }
    }
}

// ---------------------------------------------------------------------------
// Kernel 2: recurrence, ONE workgroup per (dir, 16-batch) cluster.
// 8 WGs x 256 thr (4 waves, 1 wave/SIMD, 512-VGPR budget). Each wave owns
// 128 output dims n = wv*128 + lm*8 + nt (nt=0..7). Full Wh slice resident
// per CU: 96 frags/wave in VGPRs (kt 0..11), 32 frags/wave in LDS (kt 12..15).
// h exchange is pure-LDS (hl, 16 KB) with two lgkmcnt(0)+s_barrier per step —
// the L3 slab/flag handshake (the old 2.5 us/step latency chain) is gone.
//
// hl layout: 16B granule g(khi,b) = khi*16 + (b ^ (khi&15)), khi = k>>3,
// holding h[b][khi*8 .. khi*8+8) as f16. XOR swizzle makes:
//   - A-frag reads  (khi = kt*4+lq, b = lm): conflict-free (contig 256B/phase)
//   - h writes      (khi = wv*16+lm, b = lq*4+j): 2-way (free, m136)
// MFMA frag conventions (A: h[b=lm][k=kt*32+lq*8+e]; B: Wh[n][same k];
// C: row=lq*4+j, col=lm) identical to the previously verified kernel — only
// the n-label per lane is permuted, consistently on B-load / C-write / hl.
// ---------------------------------------------------------------------------
__global__ __launch_bounds__(256, 1) void rnn_kernel(
    const _Float16* __restrict__ xp,     // [2][T][B][H] f16
    const float* __restrict__ Whf, const float* __restrict__ Whb,
    const float* __restrict__ h0f, const float* __restrict__ h0b,
    float* __restrict__ out)             // y[B][T][2H] ++ hTf ++ hTb
{
    const int blk  = blockIdx.x;         // 0..7
    const int dir  = blk >> 2;
    const int b0   = (blk & 3) * 16;
    const int tid  = threadIdx.x;
    const int wv   = tid >> 6;
    const int lane = tid & 63;
    const int lq   = lane >> 4;
    const int lm   = lane & 15;

    const float* __restrict__ Wh = dir ? Whb : Whf;
    const float* __restrict__ h0 = dir ? h0b : h0f;

    __shared__ _Float16 hl[8192];             // 16 KB: h in swizzled granules
    __shared__ _Float16 wl[4][32][64][8];     // 128 KB: per-wave LDS weight frags

    // ---- one-time: Wh rows n = wv*128 + lm*8 + nt -> f16 B-fragments ----
    half8 bw[8][12];
    {
        const float* wr0 = Wh + ((size_t)(wv*128 + lm*8)) * H_SZ + lq*8;
        #pragma unroll
        for (int nt = 0; nt < 8; nt++) {
            const float* wr = wr0 + (size_t)nt * H_SZ;
            #pragma unroll
            for (int kt = 0; kt < 16; kt++) {
                float4v lo = *(const float4v*)(wr + kt*32);
                float4v hi = *(const float4v*)(wr + kt*32 + 4);
                half8 v;
                #pragma unroll
                for (int e = 0; e < 4; e++) { v[e] = (_Float16)lo[e]; v[e+4] = (_Float16)hi[e]; }
                if (kt < 12) bw[nt][kt] = v;
                else *(half8*)&wl[wv][nt*4 + (kt - 12)][lane][0] = v;
            }
        }
    }

    // ---- stage h0 into hl (granule (khi,b) <- h0[b][khi*8..+8)) ----
    #pragma unroll
    for (int r = 0; r < 4; r++) {
        const int gi  = r*256 + tid;          // 0..1023 granules
        const int khi = gi >> 4;
        const int b   = gi & 15;
        const float* p = h0 + (size_t)(b0 + b)*H_SZ + khi*8;
        half8 v;
        #pragma unroll
        for (int e = 0; e < 8; e++) v[e] = (_Float16)p[e];
        *(half8*)&hl[(khi*16 + (b ^ (khi & 15))) * 8] = v;
    }
    __syncthreads();

    const _Float16* wlp = &wl[wv][0][lane][0];     // + frag*512 f16 (imm-foldable)

    const int ts = dir ? -1 : 1;
    const int t0 = dir ? (T_LEN - 1) : 0;
    const _Float16* xpt = xp + (((size_t)dir*T_LEN + t0)*B_SZ + (b0 + lq*4))*H_SZ
                             + wv*128 + lm*8;
    const ptrdiff_t xstep = (ptrdiff_t)ts * (B_SZ * H_SZ);
    float* yp[4];
    #pragma unroll
    for (int j = 0; j < 4; j++)
        yp[j] = out + ((size_t)(b0 + lq*4 + j)*T_LEN + t0)*1024 + dir*512 + wv*128 + lm*8;
    const ptrdiff_t ystep = (ptrdiff_t)ts * 1024;

    const int wkhi = wv*16 + lm;              // khi of this thread's output dims

    half8 xq[4];
    #pragma unroll
    for (int j = 0; j < 4; j++) xq[j] = *(const half8*)(xpt + j*H_SZ);

    #pragma unroll 1
    for (int s = 0; s < T_LEN; s++) {
        // acc init = xp (consumes xq), then prefetch next step's xp
        float4v acc[8];
        #pragma unroll
        for (int nt = 0; nt < 8; nt++)
            #pragma unroll
            for (int j = 0; j < 4; j++)
                acc[nt][j] = (float)xq[j][nt];

        if (s + 1 < T_LEN) {
            xpt += xstep;
            #pragma unroll
            for (int j = 0; j < 4; j++) xq[j] = *(const half8*)(xpt + j*H_SZ);
        }

        // MFMA: kt 0..11 weights from VGPRs
        #pragma unroll
        for (int kt = 0; kt < 12; kt++) {
            const int c = kt*4 + lq;
            half8 a = *(const half8*)&hl[(c*16 + (lm ^ (c & 15))) * 8];
            #pragma unroll
            for (int nt = 0; nt < 8; nt++)
                acc[nt] = __builtin_amdgcn_mfma_f32_16x16x32_f16(a, bw[nt][kt], acc[nt], 0, 0, 0);
        }
        // kt 12..15 weights from LDS
        #pragma unroll
        for (int kt2 = 0; kt2 < 4; kt2++) {
            const int kt = 12 + kt2;
            const int c = kt*4 + lq;
            half8 a = *(const half8*)&hl[(c*16 + (lm ^ (c & 15))) * 8];
            #pragma unroll
            for (int nt = 0; nt < 8; nt++) {
                half8 w = *(const half8*)(wlp + (nt*4 + kt2)*512);
                acc[nt] = __builtin_amdgcn_mfma_f32_16x16x32_f16(a, w, acc[nt], 0, 0, 0);
            }
        }

        // epilogue: tanh, coalesced y (and hT) stores, f16 pack
        half8 pks[4];
        #pragma unroll
        for (int j = 0; j < 4; j++) {
            float4v lo, hi;
            #pragma unroll
            for (int q = 0; q < 4; q++) {
                lo[q] = fast_tanh(acc[q][j]);
                hi[q] = fast_tanh(acc[q+4][j]);
            }
            __builtin_nontemporal_store(lo, (float4v*)yp[j]);
            __builtin_nontemporal_store(hi, (float4v*)(yp[j] + 4));
            if (s == T_LEN - 1) {
                float* hp = out + 33554432 + (size_t)dir*32768
                          + (size_t)(b0 + lq*4 + j)*H_SZ + wv*128 + lm*8;
                __builtin_nontemporal_store(lo, (float4v*)hp);
                __builtin_nontemporal_store(hi, (float4v*)(hp + 4));
            }
            yp[j] += ystep;
            half8 pk;
            #pragma unroll
            for (int q = 0; q < 4; q++) { pk[q] = (_Float16)lo[q]; pk[q+4] = (_Float16)hi[q]; }
            pks[j] = pk;
        }

        // barrier A: all waves done READING hl (lgkm only — y-stores stay in flight)
        asm volatile("s_waitcnt lgkmcnt(0)" ::: "memory");
        __builtin_amdgcn_s_barrier();

        // publish new h: one b128 per batch row, swizzled
        #pragma unroll
        for (int j = 0; j < 4; j++)
            *(half8*)&hl[(wkhi*16 + ((lq*4 + j) ^ (wkhi & 15))) * 8] = pks[j];

        // barrier B: new h visible for next step's A-frag reads
        asm volatile("s_waitcnt lgkmcnt(0)" ::: "memory");
        __builtin_amdgcn_s_barrier();
    }
}

// ---------------------------------------------------------------------------
// ws layout (bytes):
//   [0, 67108864)  xp : 2*512*64*512 f16          (slab/flags no longer needed)
// ---------------------------------------------------------------------------
extern "C" void kernel_launch(void* const* d_in, const int* in_sizes, int n_in,
                              void* d_out, int out_size, void* d_ws, size_t ws_size,
                              hipStream_t stream) {
    const float* x   = (const float*)d_in[0];
    const float* h0f = (const float*)d_in[1];
    const float* h0b = (const float*)d_in[2];
    const float* Wxf = (const float*)d_in[3];
    const float* bxf = (const float*)d_in[4];
    const float* Whf = (const float*)d_in[5];
    const float* Wxb = (const float*)d_in[6];
    const float* bxb = (const float*)d_in[7];
    const float* Whb = (const float*)d_in[8];
    float* out = (float*)d_out;

    _Float16* xpb = (_Float16*)d_ws;

    hipLaunchKernelGGL(xproj_kernel, dim3(8192), dim3(256), 0, stream,
                       x, Wxf, bxf, Wxb, bxb, xpb);
    hipLaunchKernelGGL(rnn_kernel, dim3(8), dim3(256), 0, stream,
                       xpb, Whf, Whb, h0f, h0b, out);
}

// Round 4
// 2180.851 us; speedup vs baseline: 1.0035x; 1.0035x over previous
//
#include <hip/hip_runtime.h>

#define T_LEN 512
#define B_SZ  64
#define I_SZ  512
#define H_SZ  512

using half8   = __attribute__((ext_vector_type(8))) _Float16;
using float4v = __attribute__((ext_vector_type(4))) float;

__device__ __forceinline__ float fast_tanh(float x) {
    // 1 - 2/(e^{2x}+1): monotone, saturates to +/-1, no NaN (inf -> 1, 0 -> -1)
    float e = __expf(2.0f * x);
    return 1.0f - 2.0f * __builtin_amdgcn_rcpf(e + 1.0f);
}

// ---------------------------------------------------------------------------
// Kernel 1: input projection GEMM (f16 MFMA, fp32 accumulate) — unchanged.
// ---------------------------------------------------------------------------
__global__ __launch_bounds__(256) void xproj_kernel(
    const float* __restrict__ x,
    const float* __restrict__ Wf, const float* __restrict__ bf,
    const float* __restrict__ Wb, const float* __restrict__ bb,
    _Float16* __restrict__ xp)
{
    __shared__ _Float16 Ash[64][72];
    __shared__ _Float16 Bsh[64][72];

    const int bid = blockIdx.x;
    const int dir = bid & 1;
    const int nt  = (bid >> 1) & 7;
    const int t   = bid >> 4;
    const float* __restrict__ W    = dir ? Wb : Wf;
    const float* __restrict__ bias = dir ? bb : bf;
    const int n0 = nt * 64;

    const int tid  = threadIdx.x;
    const int row  = tid >> 2;
    const int part = tid & 3;
    const int wv   = tid >> 6;
    const int lane = tid & 63;
    const int lm   = lane & 15;
    const int lq   = lane >> 4;

    float4v acc[4] = {{0,0,0,0},{0,0,0,0},{0,0,0,0},{0,0,0,0}};

    const float* ap = x + ((size_t)row * T_LEN + t) * I_SZ + part * 16;
    const float* bp = W + ((size_t)(n0 + row)) * I_SZ + part * 16;

    for (int k0 = 0; k0 < I_SZ; k0 += 64) {
        float areg[16], breg[16];
        #pragma unroll
        for (int i = 0; i < 16; i++) { areg[i] = ap[k0 + i]; breg[i] = bp[k0 + i]; }
        __syncthreads();
        #pragma unroll
        for (int i = 0; i < 16; i++) {
            Ash[row][part*16 + i] = (_Float16)areg[i];
            Bsh[row][part*16 + i] = (_Float16)breg[i];
        }
        __syncthreads();
        #pragma unroll
        for (int ks = 0; ks < 2; ks++) {
            half8 afr = *(const half8*)&Ash[16*wv + lm][ks*32 + lq*8];
            #pragma unroll
            for (int ns = 0; ns < 4; ns++) {
                half8 bfr = *(const half8*)&Bsh[ns*16 + lm][ks*32 + lq*8];
                acc[ns] = __builtin_amdgcn_mfma_f32_16x16x32_f16(afr, bfr, acc[ns], 0, 0, 0);
            }
        }
    }

    #pragma unroll
    for (int ns = 0; ns < 4; ns++) {
        const int n = n0 + ns*16 + lm;
        const float bv = bias[n];
        #pragma unroll
        for (int j = 0; j < 4; j++) {
            const int b = 16*wv + lq*4 + j;
            xp[(((size_t)dir*T_LEN + t)*B_SZ + b)*H_SZ + n] = (_Float16)(acc[ns][j] + bv);
        }
    }
}

// ---------------------------------------------------------------------------
// Kernel 2: recurrence, ONE workgroup per (dir, 16-batch) cluster.
// 8 WGs x 256 thr (4 waves, 1 wave/SIMD). Each wave owns 128 output dims
// n = wv*128 + lm*8 + nt. Weights: 96 frags/wave in registers (compiler
// places overflow in AGPRs; gfx950 MFMA reads A/B from AGPR directly —
// AV operand class, no per-use moves), 32 frags/wave in LDS (128 KB).
// THIS ROUND'S SINGLE CHANGE vs the passing R1 kernel: hoisted af[16]
// block-load of all A-fragments at loop top (the R0-proven pattern).
// R1 loaded one A-frag per kt inside the MFMA loop -> one outstanding
// ds_read at a time -> ~16 exposed ~120cy LDS latencies per step. The
// block load issues all 16 ds_read_b128 back-to-back; latency amortizes
// to one wait overlapped with the xq->acc cvt init.
// h exchange stays pure-LDS (hl, 16 KB, swizzled granules, proven).
// ---------------------------------------------------------------------------
__global__ __launch_bounds__(256, 1) void rnn_kernel(
    const _Float16* __restrict__ xp,     // [2][T][B][H] f16
    const float* __restrict__ Whf, const float* __restrict__ Whb,
    const float* __restrict__ h0f, const float* __restrict__ h0b,
    float* __restrict__ out)             // y[B][T][2H] ++ hTf ++ hTb
{
    const int blk  = blockIdx.x;         // 0..7
    const int dir  = blk >> 2;
    const int b0   = (blk & 3) * 16;
    const int tid  = threadIdx.x;
    const int wv   = tid >> 6;
    const int lane = tid & 63;
    const int lq   = lane >> 4;
    const int lm   = lane & 15;

    const float* __restrict__ Wh = dir ? Whb : Whf;
    const float* __restrict__ h0 = dir ? h0b : h0f;

    __shared__ _Float16 hl[8192];             // 16 KB: h in swizzled granules
    __shared__ _Float16 wl[4][32][64][8];     // 128 KB: per-wave LDS weight frags

    // ---- one-time: Wh rows n = wv*128 + lm*8 + nt -> f16 B-fragments ----
    half8 bw[8][12];
    {
        const float* wr0 = Wh + ((size_t)(wv*128 + lm*8)) * H_SZ + lq*8;
        #pragma unroll
        for (int nt = 0; nt < 8; nt++) {
            const float* wr = wr0 + (size_t)nt * H_SZ;
            #pragma unroll
            for (int kt = 0; kt < 16; kt++) {
                float4v lo = *(const float4v*)(wr + kt*32);
                float4v hi = *(const float4v*)(wr + kt*32 + 4);
                half8 v;
                #pragma unroll
                for (int e = 0; e < 4; e++) { v[e] = (_Float16)lo[e]; v[e+4] = (_Float16)hi[e]; }
                if (kt < 12) bw[nt][kt] = v;
                else *(half8*)&wl[wv][nt*4 + (kt - 12)][lane][0] = v;
            }
        }
    }

    // ---- stage h0 into hl (granule (khi,b) <- h0[b][khi*8..+8)) ----
    #pragma unroll
    for (int r = 0; r < 4; r++) {
        const int gi  = r*256 + tid;          // 0..1023 granules
        const int khi = gi >> 4;
        const int b   = gi & 15;
        const float* p = h0 + (size_t)(b0 + b)*H_SZ + khi*8;
        half8 v;
        #pragma unroll
        for (int e = 0; e < 8; e++) v[e] = (_Float16)p[e];
        *(half8*)&hl[(khi*16 + (b ^ (khi & 15))) * 8] = v;
    }
    __syncthreads();

    const _Float16* wlp = &wl[wv][0][lane][0];     // + frag*512 f16 (imm-foldable)

    const int ts = dir ? -1 : 1;
    const int t0 = dir ? (T_LEN - 1) : 0;
    const _Float16* xpt = xp + (((size_t)dir*T_LEN + t0)*B_SZ + (b0 + lq*4))*H_SZ
                             + wv*128 + lm*8;
    const ptrdiff_t xstep = (ptrdiff_t)ts * (B_SZ * H_SZ);
    float* yp[4];
    #pragma unroll
    for (int j = 0; j < 4; j++)
        yp[j] = out + ((size_t)(b0 + lq*4 + j)*T_LEN + t0)*1024 + dir*512 + wv*128 + lm*8;
    const ptrdiff_t ystep = (ptrdiff_t)ts * 1024;

    const int wkhi = wv*16 + lm;              // khi of this thread's output dims

    half8 xq[4];
    #pragma unroll
    for (int j = 0; j < 4; j++) xq[j] = *(const half8*)(xpt + j*H_SZ);

    #pragma unroll 1
    for (int s = 0; s < T_LEN; s++) {
        // hoisted A-fragment block load: 16 back-to-back ds_read_b128,
        // latency overlapped with the cvt init below (R0-proven pattern)
        half8 af[16];
        #pragma unroll
        for (int kt = 0; kt < 16; kt++) {
            const int c = kt*4 + lq;
            af[kt] = *(const half8*)&hl[(c*16 + (lm ^ (c & 15))) * 8];
        }

        // acc init = xp (consumes xq), then prefetch next step's xp
        float4v acc[8];
        #pragma unroll
        for (int nt = 0; nt < 8; nt++)
            #pragma unroll
            for (int j = 0; j < 4; j++)
                acc[nt][j] = (float)xq[j][nt];

        if (s + 1 < T_LEN) {
            xpt += xstep;
            #pragma unroll
            for (int j = 0; j < 4; j++) xq[j] = *(const half8*)(xpt + j*H_SZ);
        }

        // kt 0..11: B from registers (VGPR/AGPR via AV operand class)
        #pragma unroll
        for (int kt = 0; kt < 12; kt++) {
            #pragma unroll
            for (int nt = 0; nt < 8; nt++)
                acc[nt] = __builtin_amdgcn_mfma_f32_16x16x32_f16(af[kt], bw[nt][kt], acc[nt], 0, 0, 0);
        }
        // kt 12..15: B from LDS
        #pragma unroll
        for (int kt2 = 0; kt2 < 4; kt2++) {
            #pragma unroll
            for (int nt = 0; nt < 8; nt++) {
                half8 w = *(const half8*)(wlp + (nt*4 + kt2)*512);
                acc[nt] = __builtin_amdgcn_mfma_f32_16x16x32_f16(af[12+kt2], w, acc[nt], 0, 0, 0);
            }
        }

        // epilogue: tanh, coalesced y (and hT) stores, f16 pack
        half8 pks[4];
        #pragma unroll
        for (int j = 0; j < 4; j++) {
            float4v lo, hi;
            #pragma unroll
            for (int q = 0; q < 4; q++) {
                lo[q] = fast_tanh(acc[q][j]);
                hi[q] = fast_tanh(acc[q+4][j]);
            }
            __builtin_nontemporal_store(lo, (float4v*)yp[j]);
            __builtin_nontemporal_store(hi, (float4v*)(yp[j] + 4));
            if (s == T_LEN - 1) {
                float* hp = out + 33554432 + (size_t)dir*32768
                          + (size_t)(b0 + lq*4 + j)*H_SZ + wv*128 + lm*8;
                __builtin_nontemporal_store(lo, (float4v*)hp);
                __builtin_nontemporal_store(hi, (float4v*)(hp + 4));
            }
            yp[j] += ystep;
            half8 pk;
            #pragma unroll
            for (int q = 0; q < 4; q++) { pk[q] = (_Float16)lo[q]; pk[q+4] = (_Float16)hi[q]; }
            pks[j] = pk;
        }

        // barrier A: all waves done READING hl (lgkm only — y-stores stay in flight)
        asm volatile("s_waitcnt lgkmcnt(0)" ::: "memory");
        __builtin_amdgcn_s_barrier();

        // publish new h: one b128 per batch row, swizzled
        #pragma unroll
        for (int j = 0; j < 4; j++)
            *(half8*)&hl[(wkhi*16 + ((lq*4 + j) ^ (wkhi & 15))) * 8] = pks[j];

        // barrier B: new h visible for next step's A-frag reads
        asm volatile("s_waitcnt lgkmcnt(0)" ::: "memory");
        __builtin_amdgcn_s_barrier();
    }
}

// ---------------------------------------------------------------------------
// ws layout (bytes):
//   [0, 67108864)  xp : 2*512*64*512 f16
// ---------------------------------------------------------------------------
extern "C" void kernel_launch(void* const* d_in, const int* in_sizes, int n_in,
                              void* d_out, int out_size, void* d_ws, size_t ws_size,
                              hipStream_t stream) {
    const float* x   = (const float*)d_in[0];
    const float* h0f = (const float*)d_in[1];
    const float* h0b = (const float*)d_in[2];
    const float* Wxf = (const float*)d_in[3];
    const float* bxf = (const float*)d_in[4];
    const float* Whf = (const float*)d_in[5];
    const float* Wxb = (const float*)d_in[6];
    const float* bxb = (const float*)d_in[7];
    const float* Whb = (const float*)d_in[8];
    float* out = (float*)d_out;

    _Float16* xpb = (_Float16*)d_ws;

    hipLaunchKernelGGL(xproj_kernel, dim3(8192), dim3(256), 0, stream,
                       x, Wxf, bxf, Wxb, bxb, xpb);
    hipLaunchKernelGGL(rnn_kernel, dim3(8), dim3(256), 0, stream,
                       xpb, Whf, Whb, h0f, h0b, out);
}

// Round 5
// 1747.975 us; speedup vs baseline: 1.2520x; 1.2476x over previous
//
#include <hip/hip_runtime.h>

#define T_LEN 512
#define B_SZ  64
#define I_SZ  512
#define H_SZ  512

using half8   = __attribute__((ext_vector_type(8))) _Float16;
using half4   = __attribute__((ext_vector_type(4))) _Float16;
using float4v = __attribute__((ext_vector_type(4))) float;

__device__ __forceinline__ float fast_tanh(float x) {
    // 1 - 2/(e^{2x}+1): monotone, saturates to +/-1, no NaN (inf -> 1, 0 -> -1)
    float e = __expf(2.0f * x);
    return 1.0f - 2.0f * __builtin_amdgcn_rcpf(e + 1.0f);
}

// ---------------------------------------------------------------------------
// Kernel 1: input projection GEMM (f16 MFMA, fp32 accumulate) — unchanged.
// ---------------------------------------------------------------------------
__global__ __launch_bounds__(256) void xproj_kernel(
    const float* __restrict__ x,
    const float* __restrict__ Wf, const float* __restrict__ bf,
    const float* __restrict__ Wb, const float* __restrict__ bb,
    _Float16* __restrict__ xp)
{
    __shared__ _Float16 Ash[64][72];
    __shared__ _Float16 Bsh[64][72];

    const int bid = blockIdx.x;
    const int dir = bid & 1;
    const int nt  = (bid >> 1) & 7;
    const int t   = bid >> 4;
    const float* __restrict__ W    = dir ? Wb : Wf;
    const float* __restrict__ bias = dir ? bb : bf;
    const int n0 = nt * 64;

    const int tid  = threadIdx.x;
    const int row  = tid >> 2;
    const int part = tid & 3;
    const int wv   = tid >> 6;
    const int lane = tid & 63;
    const int lm   = lane & 15;
    const int lq   = lane >> 4;

    float4v acc[4] = {{0,0,0,0},{0,0,0,0},{0,0,0,0},{0,0,0,0}};

    const float* ap = x + ((size_t)row * T_LEN + t) * I_SZ + part * 16;
    const float* bp = W + ((size_t)(n0 + row)) * I_SZ + part * 16;

    for (int k0 = 0; k0 < I_SZ; k0 += 64) {
        float areg[16], breg[16];
        #pragma unroll
        for (int i = 0; i < 16; i++) { areg[i] = ap[k0 + i]; breg[i] = bp[k0 + i]; }
        __syncthreads();
        #pragma unroll
        for (int i = 0; i < 16; i++) {
            Ash[row][part*16 + i] = (_Float16)areg[i];
            Bsh[row][part*16 + i] = (_Float16)breg[i];
        }
        __syncthreads();
        #pragma unroll
        for (int ks = 0; ks < 2; ks++) {
            half8 afr = *(const half8*)&Ash[16*wv + lm][ks*32 + lq*8];
            #pragma unroll
            for (int ns = 0; ns < 4; ns++) {
                half8 bfr = *(const half8*)&Bsh[ns*16 + lm][ks*32 + lq*8];
                acc[ns] = __builtin_amdgcn_mfma_f32_16x16x32_f16(afr, bfr, acc[ns], 0, 0, 0);
            }
        }
    }

    #pragma unroll
    for (int ns = 0; ns < 4; ns++) {
        const int n = n0 + ns*16 + lm;
        const float bv = bias[n];
        #pragma unroll
        for (int j = 0; j < 4; j++) {
            const int b = 16*wv + lq*4 + j;
            xp[(((size_t)dir*T_LEN + t)*B_SZ + b)*H_SZ + n] = (_Float16)(acc[ns][j] + bv);
        }
    }
}

// ---------------------------------------------------------------------------
// Kernel 2: recurrence, ONE workgroup per (dir, 16-batch) cluster.
// R5 change: 512 threads = 8 waves = 2 waves/SIMD (was 4 waves, 1/SIMD).
// R4's counters showed the 4 waves executing nearly serially (per-CU
// MfmaUtil 23% / VALUBusy 32% match the any-SIMD-busy SUM of 4 waves) —
// 1 wave/SIMD exposes every DS/trans/hazard latency. 2 waves/SIMD lets the
// sibling wave fill the bubbles (Guideline 1).
// Each wave owns 64 output dims n = wv*64 + lm*4 + nt (nt=0..3):
//   kt 0..11 weights -> 48 half8 frags in registers (192 VGPRs; cap is
//             256/wave at 2 waves/SIMD: 8 waves x 256 = 2048/CU exactly)
//   kt 12..15 -> 16 frags/wave in LDS wl (128 KB), re-read each step.
// A-frags streamed in 4-chunks (16 regs) to fit the register budget.
// hl exchange (16 KB swizzled granules) and the two lgkm+barrier per step
// are unchanged from the proven R4 structure; intrinsic MFMAs only.
// Thread outputs are 4 CONTIGUOUS dims -> y store = one float4; h publish
// = one ds_write_b64 half-granule at byte offset (lm&1)*8.
// ---------------------------------------------------------------------------
__global__ __launch_bounds__(512, 2) void rnn_kernel(
    const _Float16* __restrict__ xp,     // [2][T][B][H] f16
    const float* __restrict__ Whf, const float* __restrict__ Whb,
    const float* __restrict__ h0f, const float* __restrict__ h0b,
    float* __restrict__ out)             // y[B][T][2H] ++ hTf ++ hTb
{
    const int blk  = blockIdx.x;         // 0..7
    const int dir  = blk >> 2;
    const int b0   = (blk & 3) * 16;
    const int tid  = threadIdx.x;
    const int wv   = tid >> 6;           // 0..7
    const int lane = tid & 63;
    const int lq   = lane >> 4;
    const int lm   = lane & 15;

    const float* __restrict__ Wh = dir ? Whb : Whf;
    const float* __restrict__ h0 = dir ? h0b : h0f;

    __shared__ _Float16 hl[8192];             // 16 KB: h in swizzled granules
    __shared__ _Float16 wl[8][16][64][8];     // 128 KB: per-wave LDS weight frags

    // ---- one-time: Wh rows n = wv*64 + lm*4 + nt -> f16 B-fragments ----
    half8 bw[4][12];
    {
        const float* wr0 = Wh + ((size_t)(wv*64 + lm*4)) * H_SZ + lq*8;
        #pragma unroll
        for (int nt = 0; nt < 4; nt++) {
            const float* wr = wr0 + (size_t)nt * H_SZ;
            #pragma unroll
            for (int kt = 0; kt < 16; kt++) {
                float4v lo = *(const float4v*)(wr + kt*32);
                float4v hi = *(const float4v*)(wr + kt*32 + 4);
                half8 v;
                #pragma unroll
                for (int e = 0; e < 4; e++) { v[e] = (_Float16)lo[e]; v[e+4] = (_Float16)hi[e]; }
                if (kt < 12) bw[nt][kt] = v;
                else *(half8*)&wl[wv][nt*4 + (kt - 12)][lane][0] = v;
            }
        }
    }

    // ---- stage h0 into hl (granule (khi,b) <- h0[b][khi*8..+8)) ----
    #pragma unroll
    for (int r = 0; r < 2; r++) {
        const int gi  = r*512 + tid;          // 0..1023 granules
        const int khi = gi >> 4;
        const int b   = gi & 15;
        const float* p = h0 + (size_t)(b0 + b)*H_SZ + khi*8;
        half8 v;
        #pragma unroll
        for (int e = 0; e < 8; e++) v[e] = (_Float16)p[e];
        *(half8*)&hl[(khi*16 + (b ^ (khi & 15))) * 8] = v;
    }
    __syncthreads();

    const _Float16* wlp = &wl[wv][0][lane][0];     // + frag*512 f16 (imm-foldable)

    const int ts = dir ? -1 : 1;
    const int t0 = dir ? (T_LEN - 1) : 0;
    const _Float16* xpt = xp + (((size_t)dir*T_LEN + t0)*B_SZ + (b0 + lq*4))*H_SZ
                             + wv*64 + lm*4;
    const ptrdiff_t xstep = (ptrdiff_t)ts * (B_SZ * H_SZ);
    float* yb = out + ((size_t)(b0 + lq*4)*T_LEN + t0)*1024 + dir*512 + wv*64 + lm*4;
    const ptrdiff_t ystep = (ptrdiff_t)ts * 1024;

    const int khiw = wv*8 + (lm >> 1);    // granule row of this thread's outputs
    const int gofs = (lm & 1) * 4;        // f16 offset within the granule

    half4 xq[4];
    #pragma unroll
    for (int j = 0; j < 4; j++) xq[j] = *(const half4*)(xpt + j*H_SZ);

    #pragma unroll 1
    for (int s = 0; s < T_LEN; s++) {
        // acc init = xp (consumes xq), then prefetch next step's xp
        float4v acc[4];
        #pragma unroll
        for (int nt = 0; nt < 4; nt++)
            #pragma unroll
            for (int j = 0; j < 4; j++)
                acc[nt][j] = (float)xq[j][nt];

        if (s + 1 < T_LEN) {
            xpt += xstep;
            #pragma unroll
            for (int j = 0; j < 4; j++) xq[j] = *(const half4*)(xpt + j*H_SZ);
        }

        // kt 0..11: B from registers, A streamed in 4-chunks
        #pragma unroll
        for (int g = 0; g < 3; g++) {
            half8 af[4];
            #pragma unroll
            for (int i = 0; i < 4; i++) {
                const int c = (g*4 + i)*4 + lq;
                af[i] = *(const half8*)&hl[(c*16 + (lm ^ (c & 15))) * 8];
            }
            #pragma unroll
            for (int i = 0; i < 4; i++)
                #pragma unroll
                for (int nt = 0; nt < 4; nt++)
                    acc[nt] = __builtin_amdgcn_mfma_f32_16x16x32_f16(af[i], bw[nt][g*4 + i], acc[nt], 0, 0, 0);
        }
        // kt 12..15: B from LDS
        {
            half8 af[4];
            #pragma unroll
            for (int i = 0; i < 4; i++) {
                const int c = (12 + i)*4 + lq;
                af[i] = *(const half8*)&hl[(c*16 + (lm ^ (c & 15))) * 8];
            }
            #pragma unroll
            for (int i = 0; i < 4; i++)
                #pragma unroll
                for (int nt = 0; nt < 4; nt++) {
                    half8 w = *(const half8*)(wlp + (nt*4 + i)*512);
                    acc[nt] = __builtin_amdgcn_mfma_f32_16x16x32_f16(af[i], w, acc[nt], 0, 0, 0);
                }
        }

        // epilogue: tanh, one float4 y store per batch row, f16 pack
        half4 pks[4];
        #pragma unroll
        for (int j = 0; j < 4; j++) {
            float4v v;
            #pragma unroll
            for (int nt = 0; nt < 4; nt++) v[nt] = fast_tanh(acc[nt][j]);
            __builtin_nontemporal_store(v, (float4v*)(yb + (size_t)j*(T_LEN*1024)));
            if (s == T_LEN - 1) {
                float* hp = out + 33554432 + (size_t)dir*32768
                          + (size_t)(b0 + lq*4 + j)*H_SZ + wv*64 + lm*4;
                __builtin_nontemporal_store(v, (float4v*)hp);
            }
            half4 pk;
            #pragma unroll
            for (int nt = 0; nt < 4; nt++) pk[nt] = (_Float16)v[nt];
            pks[j] = pk;
        }
        yb += ystep;

        // barrier A: all waves done READING hl (lgkm only — y-stores stay in flight)
        asm volatile("s_waitcnt lgkmcnt(0)" ::: "memory");
        __builtin_amdgcn_s_barrier();

        // publish new h: one b64 half-granule per batch row, swizzled
        #pragma unroll
        for (int j = 0; j < 4; j++)
            *(half4*)&hl[(khiw*16 + ((lq*4 + j) ^ (khiw & 15))) * 8 + gofs] = pks[j];

        // barrier B: new h visible for next step's A-frag reads
        asm volatile("s_waitcnt lgkmcnt(0)" ::: "memory");
        __builtin_amdgcn_s_barrier();
    }
}

// ---------------------------------------------------------------------------
// ws layout (bytes):
//   [0, 67108864)  xp : 2*512*64*512 f16
// ---------------------------------------------------------------------------
extern "C" void kernel_launch(void* const* d_in, const int* in_sizes, int n_in,
                              void* d_out, int out_size, void* d_ws, size_t ws_size,
                              hipStream_t stream) {
    const float* x   = (const float*)d_in[0];
    const float* h0f = (const float*)d_in[1];
    const float* h0b = (const float*)d_in[2];
    const float* Wxf = (const float*)d_in[3];
    const float* bxf = (const float*)d_in[4];
    const float* Whf = (const float*)d_in[5];
    const float* Wxb = (const float*)d_in[6];
    const float* bxb = (const float*)d_in[7];
    const float* Whb = (const float*)d_in[8];
    float* out = (float*)d_out;

    _Float16* xpb = (_Float16*)d_ws;

    hipLaunchKernelGGL(xproj_kernel, dim3(8192), dim3(256), 0, stream,
                       x, Wxf, bxf, Wxb, bxb, xpb);
    hipLaunchKernelGGL(rnn_kernel, dim3(8), dim3(512), 0, stream,
                       xpb, Whf, Whb, h0f, h0b, out);
}

// Round 6
// 1695.274 us; speedup vs baseline: 1.2909x; 1.0311x over previous
//
#include <hip/hip_runtime.h>

#define T_LEN 512
#define B_SZ  64
#define I_SZ  512
#define H_SZ  512

using half8   = __attribute__((ext_vector_type(8))) _Float16;
using half4   = __attribute__((ext_vector_type(4))) _Float16;
using float4v = __attribute__((ext_vector_type(4))) float;

__device__ __forceinline__ float fast_tanh(float x) {
    // 1 - 2/(e^{2x}+1): monotone, saturates to +/-1, no NaN (inf -> 1, 0 -> -1)
    float e = __expf(2.0f * x);
    return 1.0f - 2.0f * __builtin_amdgcn_rcpf(e + 1.0f);
}

// ---------------------------------------------------------------------------
// Kernel 1 (REWRITTEN this round): input projection as a proper tiled GEMM.
// C[m][n] = sum_k x[m][k] * W[n][k],  m = b*T + t (x is (B*T, I) row-major).
// Old version re-read x 16x and W per-t (~2 GB staged traffic -> ~300 us).
// New: 128x128 tile, BK=64, 256 thr (4 waves 2x2, 64x64 per wave).
// LDS uses the rnn-proven granule-XOR layout (conflict-free frag reads):
//   per 16-row panel p: granule(khi,rr) at p*1024 + (khi*16 + (rr^khi))*8,
//   khi = k>>3 (0..7 within BK=64), rr = row&15.
// Frag conventions identical to the passing kernels: A row=lq*4+j, col n=lm.
// Bijective XCD swizzle: each XCD owns contiguous m-panels -> x read ~once
// per XCD L2; W (4 MB) stays L2/L3 resident.
// ---------------------------------------------------------------------------
__global__ __launch_bounds__(256) void xproj_kernel(
    const float* __restrict__ x,
    const float* __restrict__ Wf, const float* __restrict__ bf,
    const float* __restrict__ Wb, const float* __restrict__ bb,
    _Float16* __restrict__ xp)
{
    __shared__ _Float16 Ash[8192];   // 8 panels x 1024 f16 (128 m-rows x 64 k)
    __shared__ _Float16 Bsh[8192];   // 8 panels x 1024 f16 (128 n-rows x 64 k)

    const int bid = blockIdx.x;                  // 0..2047
    const int swz = (bid & 7) * 256 + (bid >> 3);  // bijective XCD swizzle
    const int dir = swz & 1;
    const int nb  = (swz >> 1) & 3;
    const int mb  = swz >> 3;                    // 0..255
    const int m0  = mb * 128;
    const int n0  = nb * 128;

    const float* __restrict__ W    = dir ? Wb : Wf;
    const float* __restrict__ bias = dir ? bb : bf;

    const int tid  = threadIdx.x;
    const int wv   = tid >> 6;
    const int lane = tid & 63;
    const int lm   = lane & 15;
    const int lq   = lane >> 4;
    const int wm   = wv >> 1;          // m-half 0..1
    const int wn   = wv & 1;           // n-half 0..1

    // staging assignment: thread owns granules q = r*256 + tid (r=0..3) of A
    // and the same of B. granule q: row = q>>3, khi = q&7 (8 k-elems).
    int rowA[4], ldsA[4];
    #pragma unroll
    for (int r = 0; r < 4; r++) {
        const int q   = r*256 + tid;
        const int row = q >> 3;
        const int khi = q & 7;
        rowA[r] = row;
        ldsA[r] = (row >> 4)*1024 + (khi*16 + ((row & 15) ^ khi))*8;
    }

    float4v acc[4][4];
    #pragma unroll
    for (int mt = 0; mt < 4; mt++)
        #pragma unroll
        for (int nt = 0; nt < 4; nt++)
            acc[mt][nt] = (float4v){0,0,0,0};

    for (int k0 = 0; k0 < I_SZ; k0 += 64) {
        // load 8 granules (4 A + 4 B) = 16 float4 into regs
        float4v st[16];
        #pragma unroll
        for (int r = 0; r < 4; r++) {
            const int q   = r*256 + tid;
            const int khi = q & 7;
            const float* ga = x + (size_t)(m0 + rowA[r])*I_SZ + k0 + khi*8;
            const float* gb = W + (size_t)(n0 + rowA[r])*I_SZ + k0 + khi*8;
            st[r*2]     = *(const float4v*)ga;
            st[r*2 + 1] = *(const float4v*)(ga + 4);
            st[8 + r*2]     = *(const float4v*)gb;
            st[8 + r*2 + 1] = *(const float4v*)(gb + 4);
        }
        __syncthreads();   // all waves done reading LDS (previous iter frags)
        #pragma unroll
        for (int r = 0; r < 4; r++) {
            half8 va, vb;
            #pragma unroll
            for (int e = 0; e < 4; e++) {
                va[e]   = (_Float16)st[r*2][e];
                va[e+4] = (_Float16)st[r*2+1][e];
                vb[e]   = (_Float16)st[8+r*2][e];
                vb[e+4] = (_Float16)st[8+r*2+1][e];
            }
            *(half8*)&Ash[ldsA[r]] = va;
            *(half8*)&Bsh[ldsA[r]] = vb;
        }
        __syncthreads();   // staging visible

        #pragma unroll
        for (int ks = 0; ks < 2; ks++) {
            const int khi = ks*4 + lq;
            const int go  = (khi*16 + (lm ^ khi))*8;
            half8 afr[4], bfr[4];
            #pragma unroll
            for (int mt = 0; mt < 4; mt++)
                afr[mt] = *(const half8*)&Ash[(wm*4 + mt)*1024 + go];
            #pragma unroll
            for (int nt = 0; nt < 4; nt++)
                bfr[nt] = *(const half8*)&Bsh[(wn*4 + nt)*1024 + go];
            #pragma unroll
            for (int mt = 0; mt < 4; mt++)
                #pragma unroll
                for (int nt = 0; nt < 4; nt++)
                    acc[mt][nt] = __builtin_amdgcn_mfma_f32_16x16x32_f16(
                        afr[mt], bfr[nt], acc[mt][nt], 0, 0, 0);
        }
    }

    // epilogue: bias add, store f16 to xp[dir][t][b][n]  (m = b*T + t)
    #pragma unroll
    for (int nt = 0; nt < 4; nt++) {
        const int n  = n0 + wn*64 + nt*16 + lm;
        const float bv = bias[n];
        #pragma unroll
        for (int mt = 0; mt < 4; mt++) {
            #pragma unroll
            for (int j = 0; j < 4; j++) {
                const int m = m0 + wm*64 + mt*16 + lq*4 + j;
                const int b = m >> 9;          // T = 512
                const int t = m & 511;
                xp[(((size_t)dir*T_LEN + t)*B_SZ + b)*H_SZ + n] =
                    (_Float16)(acc[mt][nt][j] + bv);
            }
        }
    }
}

// ---------------------------------------------------------------------------
// Kernel 2: recurrence — UNCHANGED from the passing R5 kernel.
// 512 thr = 8 waves = 2 waves/SIMD, one WG per (dir, 16-batch) cluster.
// ---------------------------------------------------------------------------
__global__ __launch_bounds__(512, 2) void rnn_kernel(
    const _Float16* __restrict__ xp,     // [2][T][B][H] f16
    const float* __restrict__ Whf, const float* __restrict__ Whb,
    const float* __restrict__ h0f, const float* __restrict__ h0b,
    float* __restrict__ out)             // y[B][T][2H] ++ hTf ++ hTb
{
    const int blk  = blockIdx.x;         // 0..7
    const int dir  = blk >> 2;
    const int b0   = (blk & 3) * 16;
    const int tid  = threadIdx.x;
    const int wv   = tid >> 6;           // 0..7
    const int lane = tid & 63;
    const int lq   = lane >> 4;
    const int lm   = lane & 15;

    const float* __restrict__ Wh = dir ? Whb : Whf;
    const float* __restrict__ h0 = dir ? h0b : h0f;

    __shared__ _Float16 hl[8192];             // 16 KB: h in swizzled granules
    __shared__ _Float16 wl[8][16][64][8];     // 128 KB: per-wave LDS weight frags

    // ---- one-time: Wh rows n = wv*64 + lm*4 + nt -> f16 B-fragments ----
    half8 bw[4][12];
    {
        const float* wr0 = Wh + ((size_t)(wv*64 + lm*4)) * H_SZ + lq*8;
        #pragma unroll
        for (int nt = 0; nt < 4; nt++) {
            const float* wr = wr0 + (size_t)nt * H_SZ;
            #pragma unroll
            for (int kt = 0; kt < 16; kt++) {
                float4v lo = *(const float4v*)(wr + kt*32);
                float4v hi = *(const float4v*)(wr + kt*32 + 4);
                half8 v;
                #pragma unroll
                for (int e = 0; e < 4; e++) { v[e] = (_Float16)lo[e]; v[e+4] = (_Float16)hi[e]; }
                if (kt < 12) bw[nt][kt] = v;
                else *(half8*)&wl[wv][nt*4 + (kt - 12)][lane][0] = v;
            }
        }
    }

    // ---- stage h0 into hl (granule (khi,b) <- h0[b][khi*8..+8)) ----
    #pragma unroll
    for (int r = 0; r < 2; r++) {
        const int gi  = r*512 + tid;          // 0..1023 granules
        const int khi = gi >> 4;
        const int b   = gi & 15;
        const float* p = h0 + (size_t)(b0 + b)*H_SZ + khi*8;
        half8 v;
        #pragma unroll
        for (int e = 0; e < 8; e++) v[e] = (_Float16)p[e];
        *(half8*)&hl[(khi*16 + (b ^ (khi & 15))) * 8] = v;
    }
    __syncthreads();

    const _Float16* wlp = &wl[wv][0][lane][0];     // + frag*512 f16 (imm-foldable)

    const int ts = dir ? -1 : 1;
    const int t0 = dir ? (T_LEN - 1) : 0;
    const _Float16* xpt = xp + (((size_t)dir*T_LEN + t0)*B_SZ + (b0 + lq*4))*H_SZ
                             + wv*64 + lm*4;
    const ptrdiff_t xstep = (ptrdiff_t)ts * (B_SZ * H_SZ);
    float* yb = out + ((size_t)(b0 + lq*4)*T_LEN + t0)*1024 + dir*512 + wv*64 + lm*4;
    const ptrdiff_t ystep = (ptrdiff_t)ts * 1024;

    const int khiw = wv*8 + (lm >> 1);    // granule row of this thread's outputs
    const int gofs = (lm & 1) * 4;        // f16 offset within the granule

    half4 xq[4];
    #pragma unroll
    for (int j = 0; j < 4; j++) xq[j] = *(const half4*)(xpt + j*H_SZ);

    #pragma unroll 1
    for (int s = 0; s < T_LEN; s++) {
        // acc init = xp (consumes xq), then prefetch next step's xp
        float4v acc[4];
        #pragma unroll
        for (int nt = 0; nt < 4; nt++)
            #pragma unroll
            for (int j = 0; j < 4; j++)
                acc[nt][j] = (float)xq[j][nt];

        if (s + 1 < T_LEN) {
            xpt += xstep;
            #pragma unroll
            for (int j = 0; j < 4; j++) xq[j] = *(const half4*)(xpt + j*H_SZ);
        }

        // kt 0..11: B from registers, A streamed in 4-chunks
        #pragma unroll
        for (int g = 0; g < 3; g++) {
            half8 af[4];
            #pragma unroll
            for (int i = 0; i < 4; i++) {
                const int c = (g*4 + i)*4 + lq;
                af[i] = *(const half8*)&hl[(c*16 + (lm ^ (c & 15))) * 8];
            }
            #pragma unroll
            for (int i = 0; i < 4; i++)
                #pragma unroll
                for (int nt = 0; nt < 4; nt++)
                    acc[nt] = __builtin_amdgcn_mfma_f32_16x16x32_f16(af[i], bw[nt][g*4 + i], acc[nt], 0, 0, 0);
        }
        // kt 12..15: B from LDS
        {
            half8 af[4];
            #pragma unroll
            for (int i = 0; i < 4; i++) {
                const int c = (12 + i)*4 + lq;
                af[i] = *(const half8*)&hl[(c*16 + (lm ^ (c & 15))) * 8];
            }
            #pragma unroll
            for (int i = 0; i < 4; i++)
                #pragma unroll
                for (int nt = 0; nt < 4; nt++) {
                    half8 w = *(const half8*)(wlp + (nt*4 + i)*512);
                    acc[nt] = __builtin_amdgcn_mfma_f32_16x16x32_f16(af[i], w, acc[nt], 0, 0, 0);
                }
        }

        // epilogue: tanh, one float4 y store per batch row, f16 pack
        half4 pks[4];
        #pragma unroll
        for (int j = 0; j < 4; j++) {
            float4v v;
            #pragma unroll
            for (int nt = 0; nt < 4; nt++) v[nt] = fast_tanh(acc[nt][j]);
            __builtin_nontemporal_store(v, (float4v*)(yb + (size_t)j*(T_LEN*1024)));
            if (s == T_LEN - 1) {
                float* hp = out + 33554432 + (size_t)dir*32768
                          + (size_t)(b0 + lq*4 + j)*H_SZ + wv*64 + lm*4;
                __builtin_nontemporal_store(v, (float4v*)hp);
            }
            half4 pk;
            #pragma unroll
            for (int nt = 0; nt < 4; nt++) pk[nt] = (_Float16)v[nt];
            pks[j] = pk;
        }
        yb += ystep;

        // barrier A: all waves done READING hl (lgkm only — y-stores stay in flight)
        asm volatile("s_waitcnt lgkmcnt(0)" ::: "memory");
        __builtin_amdgcn_s_barrier();

        // publish new h: one b64 half-granule per batch row, swizzled
        #pragma unroll
        for (int j = 0; j < 4; j++)
            *(half4*)&hl[(khiw*16 + ((lq*4 + j) ^ (khiw & 15))) * 8 + gofs] = pks[j];

        // barrier B: new h visible for next step's A-frag reads
        asm volatile("s_waitcnt lgkmcnt(0)" ::: "memory");
        __builtin_amdgcn_s_barrier();
    }
}

// ---------------------------------------------------------------------------
// ws layout (bytes):
//   [0, 67108864)  xp : 2*512*64*512 f16
// ---------------------------------------------------------------------------
extern "C" void kernel_launch(void* const* d_in, const int* in_sizes, int n_in,
                              void* d_out, int out_size, void* d_ws, size_t ws_size,
                              hipStream_t stream) {
    const float* x   = (const float*)d_in[0];
    const float* h0f = (const float*)d_in[1];
    const float* h0b = (const float*)d_in[2];
    const float* Wxf = (const float*)d_in[3];
    const float* bxf = (const float*)d_in[4];
    const float* Whf = (const float*)d_in[5];
    const float* Wxb = (const float*)d_in[6];
    const float* bxb = (const float*)d_in[7];
    const float* Whb = (const float*)d_in[8];
    float* out = (float*)d_out;

    _Float16* xpb = (_Float16*)d_ws;

    hipLaunchKernelGGL(xproj_kernel, dim3(2048), dim3(256), 0, stream,
                       x, Wxf, bxf, Wxb, bxb, xpb);
    hipLaunchKernelGGL(rnn_kernel, dim3(8), dim3(512), 0, stream,
                       xpb, Whf, Whb, h0f, h0b, out);
}